// Round 1
// 12321.066 us; speedup vs baseline: 1.1183x; 1.1183x over previous
//
#include <hip/hip_runtime.h>

// ---------------------------------------------------------------------------
// VQVAE forward, MI355X. Round 4 (polish): structural rework of the two
// dominant costs identified by dispatch-structure analysis:
//  1) LSTM steps: fused GEMM+gate kernel (one dispatch/step, no g round-trip)
//  2) Big GEMMs: 128x128x8 tile, 8x8/thread (4x FMA:LDS ratio vs 64x64/4x4)
// Numerics: fp32 compute everywhere, same per-accumulator k-order as before.
// B=128 T=64 V=10000 NI=512 ENC_NH=640 DEC_NH=1024 NZ=128 ND=8 K=1024 D=160
// ---------------------------------------------------------------------------

typedef unsigned short u16;
typedef unsigned int u32;

__device__ __forceinline__ float b2f(u16 u) {
    union { u32 i; float f; } v; v.i = ((u32)u) << 16; return v.f;
}
__device__ __forceinline__ u16 f2b(float f) {
    union { float f; u32 i; } v; v.f = f;
    u32 x = v.i;
    u32 r = x + 0x7FFFu + ((x >> 16) & 1u);  // RNE
    return (u16)(r >> 16);
}
__device__ __forceinline__ float sigmoidf(float x) {
    return 1.0f / (1.0f + expf(-x));
}
// flag: 1 = inputs/outputs bf16, 0 = fp32
__device__ __forceinline__ float ldin(const void* p, size_t i, int bf) {
    return bf ? b2f(((const u16*)p)[i]) : ((const float*)p)[i];
}
__device__ __forceinline__ void stout(void* p, size_t i, float v, int bf) {
    if (bf) ((u16*)p)[i] = f2b(v); else ((float*)p)[i] = v;
}

// ---------------------------------------------------------------------------
// Dtype probe (unchanged, proven): exponent-field histogram on enc_embed.
// ---------------------------------------------------------------------------
__global__ void probe_dtype(const void* emb, int* flag)
{
    __shared__ int cnt[128];
    int tid = threadIdx.x;
    u16 u = ((const u16*)emb)[2 * tid];
    int e = (u >> 7) & 0xFF;
    cnt[tid] = (e >= 100 && e <= 127) ? 1 : 0;
    __syncthreads();
    for (int s = 64; s > 0; s >>= 1) {
        if (tid < s) cnt[tid] += cnt[tid + s];
        __syncthreads();
    }
    if (tid == 0) *flag = (cnt[0] >= 96) ? 1 : 0;
}

__global__ void zero_kernel(float* p, int n)
{
    int i = blockIdx.x * 256 + threadIdx.x;
    if (i < n) p[i] = 0.0f;
}

// ---------------------------------------------------------------------------
// Small-GEMM kernel (unchanged, proven): 64x64 tile, 4x4/thread.
// Used only for the tiny M=128 GEMMs (enc_lin, z2dec, suffix).
// ---------------------------------------------------------------------------
template <int FINAL>
__global__ __launch_bounds__(256) void gemm_kernel(
    const float* __restrict__ A, int lda,
    const void* __restrict__ Wv,
    const void* __restrict__ biasv,
    void* __restrict__ Cv, int ldc,
    int M, int N, int K, const int* __restrict__ flagp)
{
    __shared__ float As[16][68];
    __shared__ float Ws[16][68];

    const int bf   = *flagp;
    const int tid  = threadIdx.x;
    const int tx   = tid & 15;
    const int ty   = tid >> 4;
    const int row0 = blockIdx.y << 6;
    const int col0 = blockIdx.x << 6;
    const int lm   = tid >> 2;
    const int lk   = (tid & 3) << 2;

    const float* Ap = A + (size_t)(row0 + lm) * lda + lk;
    const int wn    = col0 + lm;
    const bool wok  = wn < N;
    const size_t woff = (size_t)(wok ? wn : 0) * K + lk;

    float acc[4][4];
#pragma unroll
    for (int i = 0; i < 4; i++)
#pragma unroll
        for (int j = 0; j < 4; j++) acc[i][j] = 0.0f;

    for (int kt = 0; kt < K; kt += 16) {
        float4 av = *reinterpret_cast<const float4*>(Ap + kt);
        float w0 = 0.f, w1 = 0.f, w2 = 0.f, w3 = 0.f;
        if (wok) {
            if (bf) {
                ushort4 wv = *reinterpret_cast<const ushort4*>((const u16*)Wv + woff + kt);
                w0 = b2f(wv.x); w1 = b2f(wv.y); w2 = b2f(wv.z); w3 = b2f(wv.w);
            } else {
                float4 wv = *reinterpret_cast<const float4*>((const float*)Wv + woff + kt);
                w0 = wv.x; w1 = wv.y; w2 = wv.z; w3 = wv.w;
            }
        }
        As[lk + 0][lm] = av.x; As[lk + 1][lm] = av.y;
        As[lk + 2][lm] = av.z; As[lk + 3][lm] = av.w;
        Ws[lk + 0][lm] = w0; Ws[lk + 1][lm] = w1;
        Ws[lk + 2][lm] = w2; Ws[lk + 3][lm] = w3;
        __syncthreads();
#pragma unroll
        for (int kk = 0; kk < 16; kk++) {
            float a4[4], b4[4];
#pragma unroll
            for (int i = 0; i < 4; i++) a4[i] = As[kk][(ty << 2) + i];
#pragma unroll
            for (int j = 0; j < 4; j++) b4[j] = Ws[kk][(tx << 2) + j];
#pragma unroll
            for (int i = 0; i < 4; i++)
#pragma unroll
                for (int j = 0; j < 4; j++) acc[i][j] += a4[i] * b4[j];
        }
        __syncthreads();
    }

#pragma unroll
    for (int i = 0; i < 4; i++) {
        const int r = row0 + (ty << 2) + i;
#pragma unroll
        for (int j = 0; j < 4; j++) {
            const int cc = col0 + (tx << 2) + j;
            if (cc < N) {
                float v = acc[i][j];
                if (biasv) v += ldin(biasv, cc, bf);
                if (FINAL) stout(Cv, (size_t)r * ldc + cc, v, bf);
                else       ((float*)Cv)[(size_t)r * ldc + cc] = v;
            }
        }
    }
}

// ---------------------------------------------------------------------------
// Big-GEMM kernel: 128x128 tile, BK=8, 8x8 per thread (256 threads).
// C(M,N) = A(M,K fp32) @ W(N,K in-dtype)^T [+ bias]. M mult 128, K mult 8,
// N mult 4 (bounds-checked per 4-col group). FINAL=1 -> store in out-dtype.
// FMA:LDS per kk per wave = 64 FMA : 4 ds_read_b128 (vs 16:2 in gemm_kernel).
// ---------------------------------------------------------------------------
template <int FINAL>
__global__ __launch_bounds__(256) void gemm128(
    const float* __restrict__ A, int lda,
    const void* __restrict__ Wv,
    const void* __restrict__ biasv,
    void* __restrict__ Cv, int ldc,
    int M, int N, int K, const int* __restrict__ flagp)
{
    __shared__ float As[8][132];
    __shared__ float Ws[8][132];

    const int bf   = *flagp;
    const int tid  = threadIdx.x;
    const int tx   = tid & 15;          // 8-col group
    const int ty   = tid >> 4;          // 8-row group
    const int row0 = blockIdx.y << 7;
    const int col0 = blockIdx.x << 7;
    const int lr   = tid >> 1;          // 0..127: load row (A) / col (W)
    const int lk   = (tid & 1) << 2;    // 0 or 4

    const float* Ap = A + (size_t)(row0 + lr) * lda + lk;
    const int wn    = col0 + lr;
    const bool wok  = wn < N;
    const size_t woff = (size_t)(wok ? wn : 0) * K + lk;

    float acc[8][8];
#pragma unroll
    for (int i = 0; i < 8; i++)
#pragma unroll
        for (int j = 0; j < 8; j++) acc[i][j] = 0.0f;

    for (int kt = 0; kt < K; kt += 8) {
        float4 av = *reinterpret_cast<const float4*>(Ap + kt);
        float w0 = 0.f, w1 = 0.f, w2 = 0.f, w3 = 0.f;
        if (wok) {
            if (bf) {
                ushort4 wv = *reinterpret_cast<const ushort4*>((const u16*)Wv + woff + kt);
                w0 = b2f(wv.x); w1 = b2f(wv.y); w2 = b2f(wv.z); w3 = b2f(wv.w);
            } else {
                float4 wv = *reinterpret_cast<const float4*>((const float*)Wv + woff + kt);
                w0 = wv.x; w1 = wv.y; w2 = wv.z; w3 = wv.w;
            }
        }
        As[lk + 0][lr] = av.x; As[lk + 1][lr] = av.y;
        As[lk + 2][lr] = av.z; As[lk + 3][lr] = av.w;
        Ws[lk + 0][lr] = w0; Ws[lk + 1][lr] = w1;
        Ws[lk + 2][lr] = w2; Ws[lk + 3][lr] = w3;
        __syncthreads();
#pragma unroll
        for (int kk = 0; kk < 8; kk++) {
            float4 av0 = *reinterpret_cast<const float4*>(&As[kk][ty << 3]);
            float4 av1 = *reinterpret_cast<const float4*>(&As[kk][(ty << 3) + 4]);
            float4 bv0 = *reinterpret_cast<const float4*>(&Ws[kk][tx << 3]);
            float4 bv1 = *reinterpret_cast<const float4*>(&Ws[kk][(tx << 3) + 4]);
            float a8[8] = {av0.x, av0.y, av0.z, av0.w, av1.x, av1.y, av1.z, av1.w};
            float b8[8] = {bv0.x, bv0.y, bv0.z, bv0.w, bv1.x, bv1.y, bv1.z, bv1.w};
#pragma unroll
            for (int i = 0; i < 8; i++)
#pragma unroll
                for (int j = 0; j < 8; j++) acc[i][j] += a8[i] * b8[j];
        }
        __syncthreads();
    }

#pragma unroll
    for (int i = 0; i < 8; i++) {
        const size_t r = row0 + (ty << 3) + i;
#pragma unroll
        for (int jq = 0; jq < 2; jq++) {
            const int cc = col0 + (tx << 3) + (jq << 2);
            if (cc < N) {  // N mult of 4 -> whole group in/out
                float v0 = acc[i][jq * 4 + 0], v1 = acc[i][jq * 4 + 1];
                float v2 = acc[i][jq * 4 + 2], v3 = acc[i][jq * 4 + 3];
                if (biasv) {
                    v0 += ldin(biasv, cc + 0, bf); v1 += ldin(biasv, cc + 1, bf);
                    v2 += ldin(biasv, cc + 2, bf); v3 += ldin(biasv, cc + 3, bf);
                }
                if (FINAL && bf) {
                    ushort4 o; o.x = f2b(v0); o.y = f2b(v1); o.z = f2b(v2); o.w = f2b(v3);
                    *reinterpret_cast<ushort4*>((u16*)Cv + r * ldc + cc) = o;
                } else {
                    float4 o; o.x = v0; o.y = v1; o.z = v2; o.w = v3;
                    *reinterpret_cast<float4*>((float*)Cv + r * ldc + cc) = o;
                }
            }
        }
    }
}

// ---------------------------------------------------------------------------
// Fused LSTM step: block computes a 64-row x (16 j-cols x 4 gates) tile of
// g = h_{t-1} @ Whh^T, then applies gates in the epilogue (LDS exchange) and
// updates c in-place and writes h_t to hout. hin/hout have row strides so the
// decoder can read/write decout rows directly (t-1 -> t; no WAR hazard since
// hin and hout rows are distinct memory).
// Grid: (H/16, 2). Rows = 128 batch. BK=32.
// ---------------------------------------------------------------------------
__global__ __launch_bounds__(256) void lstm_step(
    const float* __restrict__ hin, int hin_rs,
    const void* __restrict__ Whh,    // (4H, H) in-dtype
    const float* __restrict__ xg,    // (128, T, 4H) fp32
    float* __restrict__ c,           // (128, H) fp32, in-place
    float* __restrict__ hout, int hout_rs,
    int H, int t, int T, const int* __restrict__ flagp)
{
    __shared__ float smem[4352];                       // 17 KB
    float (*As)[68] = (float (*)[68])smem;             // [32][68]
    float (*Ws)[68] = (float (*)[68])(smem + 2176);    // [32][68]
    float (*Cs)[68] = (float (*)[68])smem;             // [64][68] (epilogue)

    const int bf   = *flagp;
    const int tid  = threadIdx.x;
    const int tx   = tid & 15;
    const int ty   = tid >> 4;
    const int row0 = blockIdx.y << 6;     // 0 or 64
    const int j0   = blockIdx.x << 4;     // j block (16 cols)
    const int lm   = tid >> 2;            // 0..63
    const int lk   = (tid & 3) << 2;      // 0,4,8,12 (+16 for second half)

    const float* Ap = hin + (size_t)(row0 + lm) * hin_rs;
    const int gate  = lm >> 4;
    const int jj    = lm & 15;
    const size_t wbase = (size_t)(gate * H + j0 + jj) * H;

    float acc[4][4];
#pragma unroll
    for (int i = 0; i < 4; i++)
#pragma unroll
        for (int j = 0; j < 4; j++) acc[i][j] = 0.0f;

    for (int kt = 0; kt < H; kt += 32) {
        float4 a0 = *reinterpret_cast<const float4*>(Ap + kt + lk);
        float4 a1 = *reinterpret_cast<const float4*>(Ap + kt + lk + 16);
        float w0[4], w1[4];
        if (bf) {
            const u16* wp = (const u16*)Whh + wbase + kt + lk;
            ushort4 u0 = *reinterpret_cast<const ushort4*>(wp);
            ushort4 u1 = *reinterpret_cast<const ushort4*>(wp + 16);
            w0[0] = b2f(u0.x); w0[1] = b2f(u0.y); w0[2] = b2f(u0.z); w0[3] = b2f(u0.w);
            w1[0] = b2f(u1.x); w1[1] = b2f(u1.y); w1[2] = b2f(u1.z); w1[3] = b2f(u1.w);
        } else {
            const float* wp = (const float*)Whh + wbase + kt + lk;
            float4 f0 = *reinterpret_cast<const float4*>(wp);
            float4 f1 = *reinterpret_cast<const float4*>(wp + 16);
            w0[0] = f0.x; w0[1] = f0.y; w0[2] = f0.z; w0[3] = f0.w;
            w1[0] = f1.x; w1[1] = f1.y; w1[2] = f1.z; w1[3] = f1.w;
        }
        As[lk + 0][lm]  = a0.x; As[lk + 1][lm]  = a0.y;
        As[lk + 2][lm]  = a0.z; As[lk + 3][lm]  = a0.w;
        As[lk + 16][lm] = a1.x; As[lk + 17][lm] = a1.y;
        As[lk + 18][lm] = a1.z; As[lk + 19][lm] = a1.w;
        Ws[lk + 0][lm]  = w0[0]; Ws[lk + 1][lm]  = w0[1];
        Ws[lk + 2][lm]  = w0[2]; Ws[lk + 3][lm]  = w0[3];
        Ws[lk + 16][lm] = w1[0]; Ws[lk + 17][lm] = w1[1];
        Ws[lk + 18][lm] = w1[2]; Ws[lk + 19][lm] = w1[3];
        __syncthreads();
#pragma unroll
        for (int kk = 0; kk < 32; kk++) {
            float4 av = *reinterpret_cast<const float4*>(&As[kk][ty << 2]);
            float4 bv = *reinterpret_cast<const float4*>(&Ws[kk][tx << 2]);
            float a4[4] = {av.x, av.y, av.z, av.w};
            float b4[4] = {bv.x, bv.y, bv.z, bv.w};
#pragma unroll
            for (int i = 0; i < 4; i++)
#pragma unroll
                for (int j = 0; j < 4; j++) acc[i][j] += a4[i] * b4[j];
        }
        __syncthreads();
    }

    // exchange partial g through LDS (Cs overlays As/Ws; safe after barrier)
#pragma unroll
    for (int i = 0; i < 4; i++)
#pragma unroll
        for (int j = 0; j < 4; j++)
            Cs[(ty << 2) + i][(tx << 2) + j] = acc[i][j];
    __syncthreads();

    // gates: 64 rows x 16 j = 1024 elems / 256 threads = 4 reps
#pragma unroll
    for (int rep = 0; rep < 4; rep++) {
        const int idx = rep * 256 + tid;
        const int rl  = idx >> 4;
        const int j2  = idx & 15;
        const int r   = row0 + rl;
        const int j   = j0 + j2;
        const float* xr = xg + (size_t)(r * T + t) * (4 * (size_t)H);
        float gi = Cs[rl][j2]      + xr[j];
        float gf = Cs[rl][16 + j2] + xr[H + j];
        float gg = Cs[rl][32 + j2] + xr[2 * H + j];
        float go = Cs[rl][48 + j2] + xr[3 * H + j];
        const size_t ci = (size_t)r * H + j;
        float cv = sigmoidf(gf) * c[ci] + sigmoidf(gi) * tanhf(gg);
        float hv = sigmoidf(go) * tanhf(cv);
        c[ci] = cv;
        hout[(size_t)r * hout_rs + j] = hv;
    }
}

// we[r,i] = enc_embed[x[r],i]; werev[b*64+(63-t), i] = we[b*64+t, i]
__global__ void gather_enc(const int* __restrict__ x, const void* __restrict__ emb,
                           float* __restrict__ we, float* __restrict__ werev,
                           const int* __restrict__ flagp)
{
    int bf = *flagp;
    int idx = blockIdx.x * 256 + threadIdx.x;
    int r = idx >> 9, i = idx & 511;
    float v = ldin(emb, (size_t)x[r] * 512 + i, bf);
    we[idx] = v;
    int b = r >> 6, t = r & 63;
    werev[(((size_t)(b * 64 + (63 - t))) << 9) + i] = v;
}

// demb[r,i] = dec_embed[x[r],i] + suffix[b,i]
__global__ void demb_kernel(const int* __restrict__ x, const void* __restrict__ emb,
                            const float* __restrict__ suffix, float* __restrict__ out,
                            const int* __restrict__ flagp)
{
    int bf = *flagp;
    int idx = blockIdx.x * 256 + threadIdx.x;
    int r = idx >> 9, i = idx & 511;
    out[idx] = ldin(emb, (size_t)x[r] * 512 + i, bf) + suffix[((size_t)(r >> 6) << 9) + i];
}

__global__ void copy_h(const float* __restrict__ h, float* __restrict__ fhs, int H, int off)
{
    int idx = blockIdx.x * 256 + threadIdx.x;
    if (idx >= 128 * H) return;
    int b = idx / H, j = idx - b * H;
    fhs[b * 1280 + off + j] = h[idx];
}

__global__ void dec_init(const float* __restrict__ root, float* __restrict__ h, float* __restrict__ c)
{
    int idx = blockIdx.x * 256 + threadIdx.x;  // 128*1024
    float r = root[idx];
    h[idx] = tanhf(r);
    c[idx] = r;
}

// kl[b] = 0.5*sum_j(mu^2 + exp(lv) - lv - 1) -> out element OFF_KL+b
__global__ void kl_kernel(const float* __restrict__ ml, void* __restrict__ outv,
                          const int* __restrict__ flagp)
{
    const size_t OFF_KL = 81920128;
    int b = blockIdx.x, j = threadIdx.x;
    float mu = ml[b * 256 + j];
    float lv = ml[b * 256 + 128 + j];
    float v = mu * mu + expf(lv) - lv - 1.0f;
    __shared__ float red[128];
    red[j] = v; __syncthreads();
    for (int s = 64; s > 0; s >>= 1) {
        if (j < s) red[j] += red[j + s];
        __syncthreads();
    }
    if (j == 0) stout(outv, OFF_KL + b, 0.5f * red[0], *flagp);
}

// Per (b,n): argmin_k ||lat||^2 + ||cb||^2 - 2 lat.cb; gather q; vq partials.
__global__ __launch_bounds__(256) void vq_kernel(
    const float* __restrict__ fhs, const void* __restrict__ cbs,
    float* __restrict__ q, float* __restrict__ vq_accum, void* __restrict__ outv,
    const int* __restrict__ flagp)
{
    const size_t OFF_IND = 81920256;
    int bf = *flagp;
    int bn = blockIdx.x;
    int b = bn >> 3, n = bn & 7;
    __shared__ float lat[160];
    __shared__ float ssc[256];
    __shared__ int   sid[256];
    __shared__ float slat2;
    __shared__ int   bestk;
    int tid = threadIdx.x;
    if (tid < 160) lat[tid] = fhs[b * 1280 + n * 160 + tid];
    __syncthreads();
    ssc[tid] = (tid < 160) ? lat[tid] * lat[tid] : 0.0f;
    __syncthreads();
    for (int s = 128; s > 0; s >>= 1) {
        if (tid < s) ssc[tid] += ssc[tid + s];
        __syncthreads();
    }
    if (tid == 0) slat2 = ssc[0];
    __syncthreads();
    float l2 = slat2;

    float best = 3.4e38f; int bi = 0;
    for (int k = tid; k < 1024; k += 256) {
        size_t cbase = (size_t)(n * 1024 + k) * 160;
        float dot = 0.0f, c2 = 0.0f;
        for (int d = 0; d < 160; d++) {
            float f = ldin(cbs, cbase + d, bf);
            dot += lat[d] * f;
            c2  += f * f;
        }
        float s = l2 + c2 - 2.0f * dot;
        if (s < best) { best = s; bi = k; }
    }
    ssc[tid] = best; sid[tid] = bi;
    __syncthreads();
    for (int s = 128; s > 0; s >>= 1) {
        if (tid < s) {
            float o = ssc[tid + s]; int oi = sid[tid + s];
            if (o < ssc[tid] || (o == ssc[tid] && oi < sid[tid])) { ssc[tid] = o; sid[tid] = oi; }
        }
        __syncthreads();
    }
    if (tid == 0) { bestk = sid[0]; stout(outv, OFF_IND + bn, (float)sid[0], bf); }
    __syncthreads();

    float part = 0.0f;
    if (tid < 160) {
        float qv = ldin(cbs, (size_t)(n * 1024 + bestk) * 160 + tid, bf);
        q[b * 1280 + n * 160 + tid] = qv;
        float df = qv - lat[tid];
        part = df * df;
    }
    ssc[tid] = part;
    __syncthreads();
    for (int s = 128; s > 0; s >>= 1) {
        if (tid < s) ssc[tid] += ssc[tid + s];
        __syncthreads();
    }
    if (tid == 0) atomicAdd(&vq_accum[b], ssc[0]);
}

// vq_loss[b] = (1+BETA) * accum / 160 -> out element OFF_VQ+b
__global__ void vq_fin(const float* __restrict__ vq_accum, void* __restrict__ outv,
                       const int* __restrict__ flagp)
{
    const size_t OFF_VQ = 81920000;
    int b = threadIdx.x;  // 128
    stout(outv, OFF_VQ + b, vq_accum[b] * (1.25f / 160.0f), *flagp);
}

// ---------------------------------------------------------------------------

extern "C" void kernel_launch(void* const* d_in, const int* in_sizes, int n_in,
                              void* d_out, int out_size, void* d_ws, size_t ws_size,
                              hipStream_t stream)
{
    const int*  x         = (const int*)d_in[0];
    const void* enc_embed = d_in[1];
    const void* enc_Wih_f = d_in[2];
    const void* enc_Whh_f = d_in[3];
    const void* enc_b_f   = d_in[4];
    const void* enc_Wih_b = d_in[5];
    const void* enc_Whh_b = d_in[6];
    const void* enc_b_b   = d_in[7];
    const void* enc_lin   = d_in[8];
    const void* z2dec_W   = d_in[9];
    const void* z2dec_b   = d_in[10];
    const void* codebooks = d_in[11];
    const void* suffix_W  = d_in[12];
    const void* dec_embed = d_in[13];
    const void* dec_Wih   = d_in[14];
    const void* dec_Whh   = d_in[15];
    const void* dec_b     = d_in[16];
    const void* pred_W    = d_in[17];

    // ---- scratch inside d_out's logits region (dead before the final GEMM,
    //      which overwrites it; kl/vq/ind outputs live beyond 163.8MB) ----
    char* ob = (char*)d_out;
    float* xg    = (float*)(ob + 0);              // dec: 8192x4096 f32 = 128MB
                                                  // enc: 8192x2560 f32 =  80MB
    float* we    = (float*)(ob + 83886080);       // enc phase, 16MB
    float* werev = (float*)(ob + 100663296);      // enc phase, 16MB
    float* demb  = (float*)(ob + 134217728);      // dec phase, 16MB (ends 151MB)

    // ---- d_ws: ~37.4MB ----
    char* wb = (char*)d_ws;
    float* decout = (float*)(wb + 0);             // 8192x1024 f32 = 33,554,432
    float* h0     = (float*)(wb + 33554432);      // 128x1024 f32
    float* h1     = (float*)(wb + 34078720);      // 128x1024 f32
    float* c      = (float*)(wb + 34603008);      // 128x1024 f32
    float* fhs    = (float*)(wb + 35127296);      // 128x1280 f32
    float* ml     = (float*)(wb + 35782656);      // 128x256  f32
    float* root   = (float*)(wb + 35913728);      // 128x1024 f32
    float* q      = (float*)(wb + 36438016);      // 128x1280 f32
    float* suffix = (float*)(wb + 37093376);      // 128x512  f32
    float* vqa    = (float*)(wb + 37355520);      // 128 f32
    int*   flag   = (int*)  (wb + 37356032);      // 1 int

    probe_dtype<<<1, 128, 0, stream>>>(enc_embed, flag);
    // zero h0,h1,c (contiguous 393216 floats) and vqa
    zero_kernel<<<1536, 256, 0, stream>>>(h0, 393216);
    zero_kernel<<<1, 128, 0, stream>>>(vqa, 128);

    // embeddings (forward + time-reversed)
    gather_enc<<<16384, 256, 0, stream>>>(x, enc_embed, we, werev, flag);

    // xg_f = we @ enc_Wih_f^T + b  (8192x2560)
    gemm128<0><<<dim3(20, 64), 256, 0, stream>>>(we, 512, enc_Wih_f, enc_b_f,
                                                 xg, 2560, 8192, 2560, 512, flag);
    {
        float* hp = h0; float* hn = h1;
        for (int t = 0; t < 64; t++) {
            lstm_step<<<dim3(40, 2), 256, 0, stream>>>(hp, 640, enc_Whh_f, xg, c,
                                                       hn, 640, 640, t, 64, flag);
            float* tmp = hp; hp = hn; hn = tmp;
        }
        copy_h<<<320, 256, 0, stream>>>(hp, fhs, 640, 0);
    }

    // backward direction
    zero_kernel<<<1536, 256, 0, stream>>>(h0, 393216);
    gemm128<0><<<dim3(20, 64), 256, 0, stream>>>(werev, 512, enc_Wih_b, enc_b_b,
                                                 xg, 2560, 8192, 2560, 512, flag);
    {
        float* hp = h0; float* hn = h1;
        for (int t = 0; t < 64; t++) {
            lstm_step<<<dim3(40, 2), 256, 0, stream>>>(hp, 640, enc_Whh_b, xg, c,
                                                       hn, 640, 640, t, 64, flag);
            float* tmp = hp; hp = hn; hn = tmp;
        }
        copy_h<<<320, 256, 0, stream>>>(hp, fhs, 640, 640);
    }

    // mu|logvar = fhs @ enc_lin^T  (128x256)
    gemm_kernel<0><<<dim3(4, 2), 256, 0, stream>>>(fhs, 1280, enc_lin, nullptr,
                                                   ml, 256, 128, 256, 1280, flag);
    kl_kernel<<<128, 128, 0, stream>>>(ml, d_out, flag);

    // root = mu @ z2dec_W^T + b  (mu = ml cols 0..127, lda 256)
    gemm_kernel<0><<<dim3(16, 2), 256, 0, stream>>>(ml, 256, z2dec_W, z2dec_b,
                                                    root, 1024, 128, 1024, 128, flag);

    vq_kernel<<<1024, 256, 0, stream>>>(fhs, codebooks, q, vqa, d_out, flag);
    vq_fin<<<1, 128, 0, stream>>>(vqa, d_out, flag);

    // suffix = q @ suffix_W^T  (128x512)
    gemm_kernel<0><<<dim3(8, 2), 256, 0, stream>>>(q, 1280, suffix_W, nullptr,
                                                   suffix, 512, 128, 512, 1280, flag);

    // demb = dec_embed[x] + suffix
    demb_kernel<<<16384, 256, 0, stream>>>(x, dec_embed, suffix, demb, flag);

    // xg_d = demb @ dec_Wih^T + b  (8192x4096)
    gemm128<0><<<dim3(32, 64), 256, 0, stream>>>(demb, 512, dec_Wih, dec_b,
                                                 xg, 4096, 8192, 4096, 512, flag);

    // decoder LSTM: h0 = tanh(root), c0 = root; h history lives in decout rows
    dec_init<<<512, 256, 0, stream>>>(root, h0, c);
    for (int t = 0; t < 64; t++) {
        const float* hin = (t == 0) ? h0 : (decout + (size_t)(t - 1) * 1024);
        const int hrs    = (t == 0) ? 1024 : 65536;
        lstm_step<<<dim3(64, 2), 256, 0, stream>>>(hin, hrs, dec_Whh, xg, c,
                                                   decout + (size_t)t * 1024, 65536,
                                                   1024, t, 64, flag);
    }

    // logits = decout @ pred_W^T -> d_out (dtype per flag; overwrites scratch)
    gemm128<1><<<dim3(79, 64), 256, 0, stream>>>(decout, 1024, pred_W, nullptr,
                                                 d_out, 10000, 8192, 10000, 1024, flag);
}